// Round 1
// baseline (287.748 us; speedup 1.0000x reference)
//
#include <hip/hip_runtime.h>
#include <hip/hip_bf16.h>
#include <cstdint>

typedef __bf16 bf16x8 __attribute__((ext_vector_type(8)));
typedef float f32x4 __attribute__((ext_vector_type(4)));
typedef uint4 __attribute__((may_alias)) uint4a;

typedef __attribute__((address_space(3))) unsigned int   lds_u32;
typedef __attribute__((address_space(1))) const unsigned int gbl_u32;

#define BATCH 4
#define SEQ   2048
#define CDIM  1024
#define NH    16
#define HD    64

#define C1SCALE 0.18033688011112042f  /* Dh^-0.5 * log2(e), folded into Q */

__device__ __forceinline__ unsigned short f2bf(float f) {
    uint32_t u = __builtin_bit_cast(uint32_t, f);
    u += 0x7fffu + ((u >> 16) & 1u);
    return (unsigned short)(u >> 16);
}

#if __has_builtin(__builtin_amdgcn_cvt_pk_bf16_f32)
typedef __bf16 bf16x2 __attribute__((ext_vector_type(2)));
__device__ __forceinline__ uint32_t pk2bf(float a, float b) {
    bf16x2 v = __builtin_amdgcn_cvt_pk_bf16_f32(a, b);
    return __builtin_bit_cast(uint32_t, v);
}
#else
__device__ __forceinline__ uint32_t pk2bf(float a, float b) {
    return (uint32_t)f2bf(a) | ((uint32_t)f2bf(b) << 16);
}
#endif

// async 16B/lane global->LDS (wave-uniform LDS base; HW writes base+lane*16)
__device__ __forceinline__ void g2l16(const unsigned short* g, unsigned short* l) {
    __builtin_amdgcn_global_load_lds((gbl_u32*)g, (lds_u32*)l, 16, 0, 0);
}

#define SWAIT(n) asm volatile("s_waitcnt vmcnt(" #n ")" ::: "memory")

// ---------------- fused prep: cvt(x) + transpose(Wqkv) + transpose(Wproj)
// ---------------- + mask scan, partitioned by blockIdx.x (block-uniform)
#define NB_CVT   8192
#define NB_TQKV  3072
#define NB_TPROJ 1024
#define NB_PREP  (NB_CVT + NB_TQKV + NB_TPROJ + 4)

__global__ __launch_bounds__(256)
void prep_kernel(const float* __restrict__ x,
                 const float* __restrict__ Wqkv,
                 const float* __restrict__ Wproj,
                 const int* __restrict__ mask,
                 unsigned short* __restrict__ xb,
                 unsigned short* __restrict__ Wqkvt,
                 unsigned short* __restrict__ Wprojt,
                 int* __restrict__ pfx, int* __restrict__ cnt) {
    __shared__ float tile[32][33];
    __shared__ int s[256];
    int bid = blockIdx.x, tid = threadIdx.x;

    if (bid < NB_CVT) {
        int i = (bid * 256 + tid) * 4;
        float4 v = *(const float4*)(x + i);
        uint2 o;
        o.x = pk2bf(v.x, v.y);
        o.y = pk2bf(v.z, v.w);
        *(uint2*)(xb + i) = o;
        return;
    }
    if (bid < NB_CVT + NB_TQKV + NB_TPROJ) {
        const float* in;
        unsigned short* out;
        int Cc, bx;
        if (bid < NB_CVT + NB_TQKV) {
            bx = bid - NB_CVT; in = Wqkv; out = Wqkvt; Cc = 3072;
        } else {
            bx = bid - NB_CVT - NB_TQKV; in = Wproj; out = Wprojt; Cc = 1024;
        }
        int nbx = Cc >> 5;
        int c0 = (bx % nbx) * 32, r0 = (bx / nbx) * 32;
        int tx = tid & 31, ty = tid >> 5;
        #pragma unroll
        for (int i = 0; i < 32; i += 8)
            tile[ty + i][tx] = in[(size_t)(r0 + ty + i) * Cc + c0 + tx];
        __syncthreads();
        #pragma unroll
        for (int i = 0; i < 32; i += 8)
            out[(size_t)(c0 + ty + i) * 1024 + r0 + tx] = f2bf(tile[tx][ty + i]);
        return;
    }
    int b = bid - (NB_CVT + NB_TQKV + NB_TPROJ);
    int keep[8], lc = 0;
    #pragma unroll
    for (int u = 0; u < 8; ++u) {
        keep[u] = (mask[b * SEQ + tid * 8 + u] > 0) ? 0 : 1;
        lc += keep[u];
    }
    s[tid] = lc;
    __syncthreads();
    for (int d = 1; d < 256; d <<= 1) {
        int w = (tid >= d) ? s[tid - d] : 0;
        __syncthreads();
        s[tid] += w;
        __syncthreads();
    }
    int pos = s[tid] - lc;
    #pragma unroll
    for (int u = 0; u < 8; ++u) {
        int idx = b * SEQ + tid * 8 + u;
        pfx[idx] = keep[u] ? pos++ : -1;
    }
    if (tid == 255) cnt[b] = s[255];
}

// ---------------- shared GEMM core: 256x128 tile, BK=32, 3-slot LDS ring,
// ---------------- counted vmcnt (never 0 in steady state), raw s_barrier,
// ---------------- setprio around MFMA cluster. 256 threads = 4 waves,
// ---------------- per-wave output 128x64 (acc[8][4]).
#define NTILES  32          /* 1024 / 32 */
#define SLOT_SH 12288       /* shorts per ring slot: A 256*32 + B 128*32 */
#define GEMM_LDS_BYTES (SLOT_SH * 3 * 2)   /* 73728 = 72 KiB */

__device__ __forceinline__ void gemm_core_256x128(
        const unsigned short* __restrict__ A,
        const unsigned short* __restrict__ Bt,
        int m0, int n0, unsigned short* lds, f32x4 (&acc)[8][4]) {
    const int tid  = threadIdx.x;
    const int wave = tid >> 6, lane = tid & 63;
    const int wm = (wave >> 1) * 128, wn = (wave & 1) * 64;
    const int l15 = lane & 15, quad = lane >> 4;
    const int srow = lane >> 2;                               // 0..15
    const int scol = (((lane & 3) ^ ((lane >> 3) & 3)) << 3); // swizzled src col

    // staging duties: A = 4 chunks (16 rows each) per wave, B = 2 chunks
    const unsigned short* gA = A  + (size_t)(m0 + wave * 64 + srow) * 1024 + scol;
    const unsigned short* gB = Bt + (size_t)(n0 + wave * 32 + srow) * 1024 + scol;
    unsigned short* dA = lds + wave * 2048;
    unsigned short* dB = lds + 8192 + wave * 1024;

    // fragment LDS offsets (constant across K-tiles; slot base added per t)
    int offA[8], offB[4];
    #pragma unroll
    for (int mi = 0; mi < 8; ++mi) {
        int r = wm + mi * 16 + l15;
        offA[mi] = r * 32 + ((quad ^ ((r >> 1) & 3)) << 3);
    }
    #pragma unroll
    for (int nj = 0; nj < 4; ++nj) {
        int r = wn + nj * 16 + l15;
        offB[nj] = 8192 + r * 32 + ((quad ^ ((r >> 1) & 3)) << 3);
    }

    auto stage_tile = [&](int tt, int slot) {
        unsigned short* da = dA + slot * SLOT_SH;
        unsigned short* db = dB + slot * SLOT_SH;
        const unsigned short* ga = gA + tt * 32;
        const unsigned short* gb = gB + tt * 32;
        g2l16(ga,             da);
        g2l16(ga + 16 * 1024, da + 512);
        g2l16(ga + 32 * 1024, da + 1024);
        g2l16(ga + 48 * 1024, da + 1536);
        g2l16(gb,             db);
        g2l16(gb + 16 * 1024, db + 512);
    };

    // prologue: stage tiles 0,1 into slots 0,1 (6 loads each)
    stage_tile(0, 0);
    stage_tile(1, 1);

    int cur = 0;   // slot of tile t
    for (int t = 0; t < NTILES; ++t) {
        if (t + 2 < NTILES) {
            int s = cur + 2; if (s >= 3) s -= 3;   // slot of t+2 == slot of t-1 (freed)
            stage_tile(t + 2, s);
        }
        // counted vmcnt: own 6 loads of tile t retired; t+1,t+2 stay in flight
        int rem = NTILES - 1 - t;
        if (rem >= 2)      SWAIT(12);
        else if (rem == 1) SWAIT(6);
        else               SWAIT(0);
        __builtin_amdgcn_sched_barrier(0);
        __builtin_amdgcn_s_barrier();        // all waves' tile-t chunks landed
        __builtin_amdgcn_sched_barrier(0);
        asm volatile("" ::: "memory");

        const unsigned short* sb = lds + cur * SLOT_SH;
        bf16x8 av[8], bv[4];
        #pragma unroll
        for (int nj = 0; nj < 4; ++nj)
            bv[nj] = __builtin_bit_cast(bf16x8, *(const uint4a*)(sb + offB[nj]));
        #pragma unroll
        for (int mi = 0; mi < 8; ++mi)
            av[mi] = __builtin_bit_cast(bf16x8, *(const uint4a*)(sb + offA[mi]));

        __builtin_amdgcn_s_setprio(1);
        #pragma unroll
        for (int mi = 0; mi < 8; ++mi)
            #pragma unroll
            for (int nj = 0; nj < 4; ++nj)
                acc[mi][nj] = __builtin_amdgcn_mfma_f32_16x16x32_bf16(av[mi], bv[nj], acc[mi][nj], 0, 0, 0);
        __builtin_amdgcn_s_setprio(0);

        asm volatile("" ::: "memory");
        __builtin_amdgcn_sched_barrier(0);
        __builtin_amdgcn_s_barrier();        // all waves done reading slot cur
        __builtin_amdgcn_sched_barrier(0);

        cur = cur + 1; if (cur >= 3) cur = 0;
    }
}

// ---------------- GEMM 1: qkv = xb @ Wqkvt^T --------------------------------
// grid 768 = 32 (M) x 24 (N), XCD-swizzled (768 % 8 == 0 -> bijective)
__global__ __launch_bounds__(256, 2)
void gemm_qkv_kernel(const unsigned short* __restrict__ A,
                     const unsigned short* __restrict__ Bt,
                     const int* __restrict__ pfx,
                     unsigned short* __restrict__ Q,
                     unsigned short* __restrict__ Kc,
                     unsigned short* __restrict__ Vct) {
    extern __shared__ unsigned short lds[];
    int lin = blockIdx.x;
    int swz = (lin & 7) * 96 + (lin >> 3);
    int m0 = (swz & 31) * 256;
    int n0 = (swz >> 5) * 128;

    f32x4 acc[8][4] = {};
    gemm_core_256x128(A, Bt, m0, n0, lds, acc);

    int tid = threadIdx.x;
    int wave = tid >> 6, lane = tid & 63;
    int wm = (wave >> 1) * 128, wn = (wave & 1) * 64;
    int l15 = lane & 15, quad = lane >> 4;

    #pragma unroll
    for (int mi = 0; mi < 8; ++mi) {
        #pragma unroll
        for (int nj = 0; nj < 4; ++nj) {
            int col = n0 + wn + nj * 16 + l15;
            int three = col >> 10;
            int h = (col >> 6) & 15;
            int d = col & 63;
            int row0 = m0 + wm + mi * 16 + quad * 4;
            int b = row0 >> 11, n = row0 & 2047;
            size_t bh = (size_t)(b * NH + h);
            if (three == 0) {
                uint32_t p01 = pk2bf(acc[mi][nj][0] * C1SCALE, acc[mi][nj][1] * C1SCALE);
                uint32_t p23 = pk2bf(acc[mi][nj][2] * C1SCALE, acc[mi][nj][3] * C1SCALE);
                size_t base = (bh * SEQ + n) * HD + d;
                Q[base]          = (unsigned short)p01;
                Q[base + HD]     = (unsigned short)(p01 >> 16);
                Q[base + 2 * HD] = (unsigned short)p23;
                Q[base + 3 * HD] = (unsigned short)(p23 >> 16);
            } else if (three == 1) {
                #pragma unroll
                for (int r = 0; r < 4; ++r) {
                    int pf = pfx[(b << 11) + n + r];
                    if (pf >= 0) Kc[(bh * SEQ + pf) * HD + d] = f2bf(acc[mi][nj][r]);
                }
            } else {
                #pragma unroll
                for (int r = 0; r < 4; ++r) {
                    int pf = pfx[(b << 11) + n + r];
                    if (pf >= 0) Vct[(bh * HD + d) * SEQ + pf] = f2bf(acc[mi][nj][r]);
                }
            }
        }
    }
}

// ---------------- GEMM 2: out = attn @ Wproj + bias (fp32 out) ------------
// grid 256 = 32 (M) x 8 (N), XCD-swizzled
__global__ __launch_bounds__(256, 2)
void gemm_proj_kernel(const unsigned short* __restrict__ A,
                      const unsigned short* __restrict__ Bt,
                      const float* __restrict__ bias,
                      float* __restrict__ Out) {
    extern __shared__ unsigned short lds[];
    int lin = blockIdx.x;
    int swz = (lin & 7) * 32 + (lin >> 3);
    int m0 = (swz & 31) * 256;
    int n0 = (swz >> 5) * 128;

    f32x4 acc[8][4] = {};
    gemm_core_256x128(A, Bt, m0, n0, lds, acc);

    int tid = threadIdx.x;
    int wave = tid >> 6, lane = tid & 63;
    int wm = (wave >> 1) * 128, wn = (wave & 1) * 64;
    int l15 = lane & 15, quad = lane >> 4;

    #pragma unroll
    for (int mi = 0; mi < 8; ++mi) {
        #pragma unroll
        for (int nj = 0; nj < 4; ++nj) {
            int col = n0 + wn + nj * 16 + l15;
            float bv = bias[col];
            #pragma unroll
            for (int r = 0; r < 4; ++r) {
                int row = m0 + wm + mi * 16 + quad * 4 + r;
                Out[(size_t)row * CDIM + col] = acc[mi][nj][r] + bv;
            }
        }
    }
}

// ---------------- Flash attention v7 + T5 setprio ---------------------------
#define SPD 72   /* sP row stride (shorts), 144B rows (16B aligned) */

__global__ __launch_bounds__(256, 4)
void flash_attn_kernel(const unsigned short* __restrict__ Q,
                       const unsigned short* __restrict__ Kg,
                       const unsigned short* __restrict__ Vt,
                       const int* __restrict__ cnt,
                       unsigned short* __restrict__ O) {
    int bh = blockIdx.x;
    int q0 = blockIdx.y * 128;
    int b = bh >> 4, h = bh & 15;
    int tid = threadIdx.x;
    int wave = tid >> 6, lane = tid & 63;
    int l15 = lane & 15, quad = lane >> 4;
    int lr = lane >> 3, lc8 = ((lane & 7) ^ lr) * 8;

    const int kn = cnt[b];

    const size_t head_off = (size_t)bh * SEQ * HD;
    const unsigned short* Qh = Q + head_off;
    const unsigned short* Kh = Kg + head_off;
    const unsigned short* Vh = Vt + head_off;   // [HD][SEQ]

    __shared__ __align__(16) unsigned short sK [64 * 64];
    __shared__ __align__(16) unsigned short sVt[64 * 64];
    __shared__ __align__(16) unsigned short sP [4][16 * SPD];  // per-wave

    bf16x8 qf[2][2];
    #pragma unroll
    for (int mt = 0; mt < 2; ++mt) {
        const unsigned short* qp = Qh + (size_t)(q0 + wave * 32 + mt * 16 + l15) * HD + quad * 8;
        qf[mt][0] = __builtin_bit_cast(bf16x8, *(const uint4a*)(qp));
        qf[mt][1] = __builtin_bit_cast(bf16x8, *(const uint4a*)(qp + 32));
    }

    bf16x8 ones;
    {
        uint4 ov;
        ov.x = ov.y = ov.z = ov.w = 0x3F803F80u;
        ones = __builtin_bit_cast(bf16x8, ov);
    }

    f32x4 oacc[2][4] = {};
    f32x4 oextra[2] = {};

    for (int k0 = 0; k0 < kn; k0 += 64) {
        #pragma unroll
        for (int it = 0; it < 2; ++it) {
            int c = wave * 2 + it;
            int gr = c * 8 + lr;
            g2l16(Kh + (size_t)(k0 + gr) * HD + lc8, &sK[c * 512]);
            g2l16(Vh + (size_t)gr * SEQ + k0 + lc8, &sVt[c * 512]);
        }
        __syncthreads();

        bool tail = (k0 + 64 > kn);   // block-uniform

        #pragma unroll
        for (int mt = 0; mt < 2; ++mt) {
            f32x4 s[4] = {};
            #pragma unroll
            for (int j = 0; j < 4; ++j) {
                int r = j * 16 + l15, sw = r & 7;
                uint4 v0 = *(const uint4a*)(&sK[r * 64 + ((quad ^ sw) * 8)]);
                uint4 v1 = *(const uint4a*)(&sK[r * 64 + (((4 + quad) ^ sw) * 8)]);
                __builtin_amdgcn_s_setprio(1);
                s[j] = __builtin_amdgcn_mfma_f32_16x16x32_bf16(qf[mt][0], __builtin_bit_cast(bf16x8, v0), s[j], 0, 0, 0);
                s[j] = __builtin_amdgcn_mfma_f32_16x16x32_bf16(qf[mt][1], __builtin_bit_cast(bf16x8, v1), s[j], 0, 0, 0);
                __builtin_amdgcn_s_setprio(0);
            }
            unsigned short* sp = &sP[wave][0];
            if (tail) {
                #pragma unroll
                for (int j = 0; j < 4; ++j) {
                    float madd = (k0 + j * 16 + l15 < kn) ? 0.f : -1e30f;
                    #pragma unroll
                    for (int r = 0; r < 4; ++r)
                        s[j][r] = __builtin_amdgcn_exp2f(s[j][r] + madd);
                }
            } else {
                #pragma unroll
                for (int j = 0; j < 4; ++j)
                    #pragma unroll
                    for (int r = 0; r < 4; ++r)
                        s[j][r] = __builtin_amdgcn_exp2f(s[j][r]);
            }
            #pragma unroll
            for (int j = 0; j < 4; ++j) {
                uint32_t p01 = pk2bf(s[j][0], s[j][1]);
                uint32_t p23 = pk2bf(s[j][2], s[j][3]);
                int base = quad * 4 * SPD + j * 16 + l15;
                sp[base]           = (unsigned short)p01;
                sp[base + SPD]     = (unsigned short)(p01 >> 16);
                sp[base + 2 * SPD] = (unsigned short)p23;
                sp[base + 3 * SPD] = (unsigned short)(p23 >> 16);
            }
            #pragma unroll
            for (int kc = 0; kc < 2; ++kc) {
                uint4 av = *(const uint4a*)(&sp[l15 * SPD + kc * 32 + quad * 8]);
                bf16x8 af = __builtin_bit_cast(bf16x8, av);
                __builtin_amdgcn_s_setprio(1);
                #pragma unroll
                for (int jd = 0; jd < 4; ++jd) {
                    int r = jd * 16 + l15;
                    int q = ((kc * 4 + quad) ^ (r & 7)) * 8;
                    uint4 bv = *(const uint4a*)(&sVt[r * 64 + q]);
                    oacc[mt][jd] = __builtin_amdgcn_mfma_f32_16x16x32_bf16(af, __builtin_bit_cast(bf16x8, bv), oacc[mt][jd], 0, 0, 0);
                }
                oextra[mt] = __builtin_amdgcn_mfma_f32_16x16x32_bf16(af, ones, oextra[mt], 0, 0, 0);
                __builtin_amdgcn_s_setprio(0);
            }
        }
        __syncthreads();
    }

    #pragma unroll
    for (int mt = 0; mt < 2; ++mt) {
        float rl[4];
        #pragma unroll
        for (int r = 0; r < 4; ++r) rl[r] = __builtin_amdgcn_rcpf(oextra[mt][r]);
        #pragma unroll
        for (int jd = 0; jd < 4; ++jd) {
            int d = jd * 16 + l15;
            size_t base = ((size_t)(b * SEQ + q0 + wave * 32 + mt * 16 + quad * 4)) * CDIM + h * HD + d;
            uint32_t p01 = pk2bf(oacc[mt][jd][0] * rl[0], oacc[mt][jd][1] * rl[1]);
            uint32_t p23 = pk2bf(oacc[mt][jd][2] * rl[2], oacc[mt][jd][3] * rl[3]);
            O[base]            = (unsigned short)p01;
            O[base + CDIM]     = (unsigned short)(p01 >> 16);
            O[base + 2 * CDIM] = (unsigned short)p23;
            O[base + 3 * CDIM] = (unsigned short)(p23 >> 16);
        }
    }
}

extern "C" void kernel_launch(void* const* d_in, const int* in_sizes, int n_in,
                              void* d_out, int out_size, void* d_ws, size_t ws_size,
                              hipStream_t stream) {
    const float* x     = (const float*)d_in[0];
    const float* Wqkv  = (const float*)d_in[1];
    const float* Wproj = (const float*)d_in[2];
    const float* bproj = (const float*)d_in[3];
    const int*   mask  = (const int*)d_in[4];
    float* out = (float*)d_out;

    char* ws = (char*)d_ws;
    unsigned short* xb     = (unsigned short*)(ws);                       // 16 MB (also attn out)
    unsigned short* Wqkvt  = (unsigned short*)(ws + (16u << 20));         // 6 MB
    unsigned short* Wprojt = (unsigned short*)(ws + (22u << 20));         // 2 MB
    unsigned short* Qb     = (unsigned short*)(ws + (24u << 20));         // 16 MB
    unsigned short* Kb     = (unsigned short*)(ws + (40u << 20));         // 16 MB
    unsigned short* Vtb    = (unsigned short*)(ws + (56u << 20));         // 16 MB, ends 72 MB
    int*            pfx    = (int*)(ws + (72u << 20));                    // 32 KB
    int*            cntb   = (int*)(ws + (72u << 20) + (32u << 10));      // 16 B

    static bool attr_set = false;
    if (!attr_set) {
        (void)hipFuncSetAttribute(reinterpret_cast<const void*>(gemm_qkv_kernel),
                                  hipFuncAttributeMaxDynamicSharedMemorySize, GEMM_LDS_BYTES);
        (void)hipFuncSetAttribute(reinterpret_cast<const void*>(gemm_proj_kernel),
                                  hipFuncAttributeMaxDynamicSharedMemorySize, GEMM_LDS_BYTES);
        attr_set = true;
    }

    prep_kernel<<<dim3(NB_PREP), dim3(256), 0, stream>>>(x, Wqkv, Wproj, mask,
                                                         xb, Wqkvt, Wprojt, pfx, cntb);
    gemm_qkv_kernel<<<dim3(768), dim3(256), GEMM_LDS_BYTES, stream>>>(xb, Wqkvt, pfx, Qb, Kb, Vtb);
    flash_attn_kernel<<<dim3(64, 16), dim3(256), 0, stream>>>(Qb, Kb, Vtb, cntb, xb);
    gemm_proj_kernel<<<dim3(256), dim3(256), GEMM_LDS_BYTES, stream>>>(xb, Wprojt, bproj, out);
}